// Round 1
// baseline (908.276 us; speedup 1.0000x reference)
//
#include <hip/hip_runtime.h>
#include <hip/hip_bf16.h>

#define Hn   89
#define Tn   120
#define BMn  64
#define LDPn 104   // LDS row pitch in bf16 elems: 208B = 52 dwords -> 2-way max bank alias (free)
#define NTHR 384   // 6 waves: one per 16-wide j-slice of the 96-padded hidden dim

using bf16   = __bf16;
using bf16x2 = __attribute__((ext_vector_type(2))) __bf16;
using bf16x8 = __attribute__((ext_vector_type(8))) __bf16;
using f32x4  = __attribute__((ext_vector_type(4))) float;

__device__ __forceinline__ float fsig(float x) {
#if __has_builtin(__builtin_amdgcn_exp2f) && __has_builtin(__builtin_amdgcn_rcpf)
  return __builtin_amdgcn_rcpf(1.f + __builtin_amdgcn_exp2f(-1.44269504f * x));
#else
  return 1.f / (1.f + exp2f(-1.44269504f * x));
#endif
}
__device__ __forceinline__ float ftanh(float x) {
#if __has_builtin(__builtin_amdgcn_exp2f) && __has_builtin(__builtin_amdgcn_rcpf)
  return 1.f - 2.f * __builtin_amdgcn_rcpf(1.f + __builtin_amdgcn_exp2f(2.88539008f * x));
#else
  return 1.f - 2.f / (1.f + exp2f(2.88539008f * x));
#endif
}

// Each block: 64 batch rows, persistent over all T steps. Wave w owns hidden
// j-slice [16w,16w+16); holds the 6 weight column-tiles (r,z,n x ih,hh) x 3
// k-tiles as register B-frags. MFMA 16x16x32 bf16; gates fully in-register
// (C/D frag: col=lane&15=j, row=(lane>>4)*4+reg -> the 6 accs align elementwise).
__global__ __launch_bounds__(NTHR, 2)
void gru_fused(const float* __restrict__ X,    // [B][T][89]
               const float* __restrict__ Wih,  // [267][89]
               const float* __restrict__ Whh,  // [267][89]
               const float* __restrict__ bih,  // [267]
               const float* __restrict__ bhh,  // [267]
               const float* __restrict__ Wm,   // [32][89]
               const float* __restrict__ bm,   // [32]
               const float* __restrict__ Wo,   // [32]
               const float* __restrict__ bo,   // [1]
               float* __restrict__ Y,          // [B] mscore | [B][32] mmetric
               int Bt)
{
  __shared__ __align__(16) bf16 Xl[BMn][LDPn];
  __shared__ __align__(16) bf16 Hl[2][BMn][LDPn];
  __shared__ float Ml[BMn][32];

  const int tid  = threadIdx.x;
  const int lane = tid & 63;
  const int wv   = tid >> 6;       // 0..5 = j-tile
  const int l15  = lane & 15;
  const int kg   = lane >> 4;      // 0..3
  const int j    = wv * 16 + l15;  // 0..95 (89..95 = pad, stays exactly 0)
  const bool jok = (j < Hn);
  const size_t brow0 = (size_t)blockIdx.x * BMn;

  // ---- weights -> persistent register B-frags (zero-padded beyond 89) ----
  bf16x8 Bf[3][2][3];  // [gate r/z/n][ih/hh][k-tile]
#pragma unroll
  for (int g = 0; g < 3; ++g)
#pragma unroll
    for (int s = 0; s < 2; ++s) {
      const float* W = s ? Whh : Wih;
#pragma unroll
      for (int kt = 0; kt < 3; ++kt) {
        bf16x8 f;
        const int k0 = kt * 32 + kg * 8;
#pragma unroll
        for (int e = 0; e < 8; ++e) {
          const int k = k0 + e;
          const float v = (jok && k < Hn) ? W[(size_t)(g * Hn + j) * Hn + k] : 0.f;
          f[e] = (bf16)v;
        }
        Bf[g][s][kt] = f;
      }
    }

  float bsr = 0.f, bsz = 0.f, bin_ = 0.f, bhn_ = 0.f;
  if (jok) {
    bsr  = bih[0 * Hn + j] + bhh[0 * Hn + j];
    bsz  = bih[1 * Hn + j] + bhh[1 * Hn + j];
    bin_ = bih[2 * Hn + j];   // n-gate: tanh(i_n + b_in + r*(h_n + b_hn))
    bhn_ = bhh[2 * Hn + j];
  }

  // ---- X prefetch slots: thread covers 8 (row, col-pair) chunks ----
  int rr[8], cc[8];
#pragma unroll
  for (int i = 0; i < 8; ++i) {
    const int p = tid + i * NTHR;        // 0..3071 over 64 rows x 48 pairs
    rr[i] = p / 48;
    cc[i] = (p - rr[i] * 48) * 2;        // 0..94
  }
  float pa[8], pb[8];

  auto issue = [&](int t) {
#pragma unroll
    for (int i = 0; i < 8; ++i) {
      const float* s2 = X + ((brow0 + rr[i]) * Tn + t) * (size_t)Hn;
      pa[i] = (cc[i]     < Hn) ? s2[cc[i]]     : 0.f;
      pb[i] = (cc[i] + 1 < Hn) ? s2[cc[i] + 1] : 0.f;
    }
  };

  issue(0);
  for (int i = tid; i < BMn * LDPn; i += NTHR) (&Hl[0][0][0])[i] = (bf16)0.f;

  float hold[BMn / 16][4];   // fp32 carry of h at this lane's (rows, j)
#pragma unroll
  for (int mt = 0; mt < BMn / 16; ++mt)
#pragma unroll
    for (int q = 0; q < 4; ++q) hold[mt][q] = 0.f;

  for (int t = 0; t < Tn; ++t) {
    // commit prefetched X to LDS (prev iter's readers passed the end barrier)
#pragma unroll
    for (int i = 0; i < 8; ++i) {
      bf16x2 v; v.x = (bf16)pa[i]; v.y = (bf16)pb[i];
      *(bf16x2*)&Xl[rr[i]][cc[i]] = v;
    }
    if (t + 1 < Tn) issue(t + 1);   // hide HBM latency under this step's compute
    __syncthreads();

    const bf16* Hc = &Hl[t & 1][0][0];
    bf16*       Hx = &Hl[(t + 1) & 1][0][0];

#pragma unroll
    for (int mt = 0; mt < BMn / 16; ++mt) {
      f32x4 air = {0,0,0,0}, aiz = {0,0,0,0}, ain = {0,0,0,0};
      f32x4 ahr = {0,0,0,0}, ahz = {0,0,0,0}, ahn = {0,0,0,0};
      const int arow = mt * 16 + l15;
#pragma unroll
      for (int kt = 0; kt < 3; ++kt) {
        const int co = kt * 32 + kg * 8;
        const bf16x8 ax = *(const bf16x8*)&Xl[arow][co];
        const bf16x8 ah = *(const bf16x8*)(Hc + arow * LDPn + co);
        air = __builtin_amdgcn_mfma_f32_16x16x32_bf16(ax, Bf[0][0][kt], air, 0, 0, 0);
        ahr = __builtin_amdgcn_mfma_f32_16x16x32_bf16(ah, Bf[0][1][kt], ahr, 0, 0, 0);
        aiz = __builtin_amdgcn_mfma_f32_16x16x32_bf16(ax, Bf[1][0][kt], aiz, 0, 0, 0);
        ahz = __builtin_amdgcn_mfma_f32_16x16x32_bf16(ah, Bf[1][1][kt], ahz, 0, 0, 0);
        ain = __builtin_amdgcn_mfma_f32_16x16x32_bf16(ax, Bf[2][0][kt], ain, 0, 0, 0);
        ahn = __builtin_amdgcn_mfma_f32_16x16x32_bf16(ah, Bf[2][1][kt], ahn, 0, 0, 0);
      }
      // gates: acc frags are elementwise-aligned (row = mt*16 + kg*4 + q, col = j)
#pragma unroll
      for (int q = 0; q < 4; ++q) {
        const float r_ = fsig(air[q] + ahr[q] + bsr);
        const float z_ = fsig(aiz[q] + ahz[q] + bsz);
        const float n_ = ftanh(ain[q] + bin_ + r_ * (ahn[q] + bhn_));
        const float hp = hold[mt][q];
        const float hv = n_ + z_ * (hp - n_);   // (1-z)*n + z*h
        hold[mt][q] = hv;
        Hx[(mt * 16 + kg * 4 + q) * LDPn + j] = (bf16)hv;
      }
    }
    __syncthreads();
  }

  // ---- epilogue: metric_fc (89->32, sigmoid) then output_fc (32->1, sigmoid) ----
  const bf16* Hf = &Hl[Tn & 1][0][0];
  for (int p = tid; p < BMn * 32; p += NTHR) {
    const int r = p >> 5, c = p & 31;
    float acc = bm[c];
    const bf16* hr2 = Hf + r * LDPn;
    for (int k = 0; k < Hn; ++k) acc = fmaf((float)hr2[k], Wm[c * Hn + k], acc);
    const float mv = fsig(acc);
    Ml[r][c] = mv;
    Y[(size_t)Bt + (brow0 + r) * 32 + c] = mv;   // out_mmetric
  }
  __syncthreads();
  if (tid < BMn) {
    float acc = bo[0];
#pragma unroll
    for (int c = 0; c < 32; ++c) acc = fmaf(Ml[tid][c], Wo[c], acc);
    Y[brow0 + tid] = fsig(acc);                  // out_mscore
  }
}

extern "C" void kernel_launch(void* const* d_in, const int* in_sizes, int n_in,
                              void* d_out, int out_size, void* d_ws, size_t ws_size,
                              hipStream_t stream) {
  const float* X   = (const float*)d_in[0];
  const float* Wih = (const float*)d_in[1];
  const float* Whh = (const float*)d_in[2];
  const float* bih = (const float*)d_in[3];
  const float* bhh = (const float*)d_in[4];
  const float* Wm  = (const float*)d_in[5];
  const float* bm  = (const float*)d_in[6];
  const float* Wo  = (const float*)d_in[7];
  const float* bo  = (const float*)d_in[8];

  const int B = in_sizes[0] / (Tn * Hn);   // 32768
  dim3 grid(B / BMn), block(NTHR);
  gru_fused<<<grid, block, 0, stream>>>(X, Wih, Whh, bih, bhh, Wm, bm, Wo, bo,
                                        (float*)d_out, B);
}